// Round 10
// baseline (560.263 us; speedup 1.0000x reference)
//
#include <hip/hip_runtime.h>
#include <hip/hip_fp16.h>
#include <hip/hip_cooperative_groups.h>

namespace cg = cooperative_groups;

#define NN 100000
#define NE 1600000
#define D  64

#define SB    256        // prep blocks (cooperative grid)
#define CHUNK 6250       // NE / SB
#define BSH   7          // bin = dst >> 7  (128 nodes per bin)
#define BMSK  127
#define NB    782        // ceil(NN / 128)
#define PAD   784        // hist row stride (ints)
#define CAPS  2560       // LDS edge capacity per bin (mean 2046, ~11 sigma)

typedef __attribute__((ext_vector_type(8))) _Float16 f16x8;
typedef __attribute__((ext_vector_type(4))) float    f32x4;

// wave-0 helper: exclusive scan of bsum[0..NB) -> binoff_l[0..NB]
__device__ __forceinline__ void scan_bsum_wave0(const int* __restrict__ bsum,
                                                int* binoff_l, int t) {
    if (t < 64) {
        int base = t * 13;                   // 64*13 = 832 >= 783
        int loc[13]; int run = 0;
#pragma unroll
        for (int j = 0; j < 13; ++j) {
            int idx = base + j;
            int v = (idx < NB) ? bsum[idx] : 0;
            loc[j] = run; run += v;
        }
        int pre = run;
#pragma unroll
        for (int off = 1; off < 64; off <<= 1) {
            int u = __shfl_up(pre, off);
            if (t >= off) pre += u;
        }
        pre -= run;                          // exclusive over lanes
#pragma unroll
        for (int j = 0; j < 13; ++j) {
            int idx = base + j;
            if (idx <= NB) binoff_l[idx] = pre + loc[j];
        }
    }
}

// ---------- fused preprocessing: hist -> scan -> scatter -> count ----------
// One cooperative kernel; grid.sync() between phases. 256 x 1024.
union PrepSM {
    int h[NB];            // phase A
    int ps[256][33];      // phase B (tiled column scan), 33.8 KB
    int cur[NB];          // phase C
    int c[128];           // phase D
};

__global__ __launch_bounds__(1024) void k_prep(
    const int* __restrict__ src, const int* __restrict__ dst,
    int* __restrict__ hist, int* __restrict__ bsum,
    unsigned* __restrict__ ebuf, float* __restrict__ dinv)
{
    __shared__ PrepSM sm;
    __shared__ int binoff_l[NB + 1];
    cg::grid_group grid = cg::this_grid();
    int t = threadIdx.x, blk = blockIdx.x;
    int e0 = blk * CHUNK;

    // ---- phase A: per-block bin histogram (LDS atomics) ----
    for (int i = t; i < NB; i += 1024) sm.h[i] = 0;
    __syncthreads();
    for (int e = e0 + t; e < e0 + CHUNK; e += 1024)
        atomicAdd(&sm.h[dst[e] >> BSH], 1);
    __syncthreads();
    for (int i = t; i < NB; i += 1024) hist[blk * PAD + i] = sm.h[i];
    __threadfence();
    grid.sync();

    // ---- phase B: per-bin exclusive scan over 256 block counts ----
    // blocks 0..24 each own a 32-bin tile; coalesced stage/writeback.
    if (blk < 25) {
        int b0 = blk * 32;
        for (int i = t; i < 256 * 32; i += 1024) {
            int r = i >> 5, cc = i & 31;
            int bin = b0 + cc;
            sm.ps[r][cc] = (bin < NB) ? hist[r * PAD + bin] : 0;
        }
        __syncthreads();
        int w = t >> 6, lane = t & 63;
        for (int cc = w; cc < 32; cc += 16) {     // wave per column
            int base = lane * 4;
            int v0 = sm.ps[base][cc], v1 = sm.ps[base + 1][cc];
            int v2 = sm.ps[base + 2][cc], v3 = sm.ps[base + 3][cc];
            int run = v0 + v1 + v2 + v3;
            int pre = run;
#pragma unroll
            for (int off = 1; off < 64; off <<= 1) {
                int u = __shfl_up(pre, off);
                if (lane >= off) pre += u;
            }
            pre -= run;
            sm.ps[base][cc]     = pre;
            sm.ps[base + 1][cc] = pre + v0;
            sm.ps[base + 2][cc] = pre + v0 + v1;
            sm.ps[base + 3][cc] = pre + v0 + v1 + v2;
            if (lane == 63 && b0 + cc < NB) bsum[b0 + cc] = pre + run;
        }
        __syncthreads();
        for (int i = t; i < 256 * 32; i += 1024) {
            int r = i >> 5, cc = i & 31;
            int bin = b0 + cc;
            if (bin < NB) hist[r * PAD + bin] = sm.ps[r][cc];
        }
    }
    __threadfence();
    grid.sync();

    // ---- phase C: scatter packed (src<<7 | dloc) into bin-contiguous ebuf ----
    scan_bsum_wave0(bsum, binoff_l, t);
    __syncthreads();
    for (int i = t; i < NB; i += 1024)
        sm.cur[i] = binoff_l[i] + hist[blk * PAD + i];   // coalesced
    __syncthreads();
    for (int e = e0 + t; e < e0 + CHUNK; e += 1024) {
        int d = dst[e];
        int p = atomicAdd(&sm.cur[d >> BSH], 1);         // LDS atomic
        ebuf[p] = ((unsigned)src[e] << BSH) | (unsigned)(d & BMSK);
    }
    __threadfence();
    grid.sync();

    // ---- phase D: per-bin degree count -> dinv (grid-stride over bins) ----
    for (int b = blk; b < NB; b += SB) {
        if (t < 128) sm.c[t] = 0;
        __syncthreads();
        int s0 = binoff_l[b], s1 = binoff_l[b + 1];
        for (int e = s0 + t; e < s1; e += 1024)
            atomicAdd(&sm.c[ebuf[e] & BMSK], 1);
        __syncthreads();
        if (t < 128) {
            int node = (b << BSH) + t;
            if (node < NN) dinv[node] = rsqrtf((float)(sm.c[t] + 1));
        }
        __syncthreads();
    }
}

// ---------- fused MFMA GEMMs: blocks [0,half): g = half(x@Wg * dinv)
//                              blocks [half,2*half): out = pos@Wp + bg + bp ----------
__global__ __launch_bounds__(256) void k_mm(
    const float* __restrict__ x, const float* __restrict__ Wg,
    const float* __restrict__ dinv, __half* __restrict__ g,
    const float* __restrict__ pos, const float* __restrict__ Wp,
    const float* __restrict__ bg, const float* __restrict__ bp,
    float* __restrict__ out)
{
    __shared__ __align__(16) _Float16 Wt[64][64];   // Wt[n][k] = W[k][n]
    int t = threadIdx.x;
    int lane = t & 63;
    int wid = t >> 6;
    int half_grid = gridDim.x >> 1;
    bool job2 = blockIdx.x >= half_grid;
    int blk = job2 ? (blockIdx.x - half_grid) : blockIdx.x;
    const float* A = job2 ? pos : x;
    const float* W = job2 ? Wp : Wg;

    // zero-pad row g[NN] (gather's invalid-edge target)
    if (blockIdx.x == 0 && t < 64) g[(long)NN * D + t] = __float2half(0.f);

    for (int i = t; i < 64 * 64; i += 256) {
        int k = i >> 6, n = i & 63;
        Wt[n][k] = (_Float16)W[i];
    }
    __syncthreads();

    int lr = lane & 15;        // A-row / C-col within tile
    int lg = lane >> 4;        // k-group / C-row-group
    int kofs = lg * 8;

    f16x8 b[4][2];             // hoisted B frags: [col-tile][k-tile]
#pragma unroll
    for (int n = 0; n < 4; ++n)
#pragma unroll
        for (int kt = 0; kt < 2; ++kt)
            b[n][kt] = *(const f16x8*)&Wt[n * 16 + lr][kt * 32 + kofs];

    float bsv[4] = {0.f, 0.f, 0.f, 0.f};
    if (job2) {
#pragma unroll
        for (int n = 0; n < 4; ++n) {
            int cc = n * 16 + lr;
            bsv[n] = bg[cc] + bp[cc];
        }
    }

    for (int rb0 = blk * 64; rb0 < NN; rb0 += half_grid * 64) {
        int rb = rb0 + wid * 16;
        int arow = rb + lr;
        int arc = arow < NN ? arow : NN - 1;
        const float4* ap = (const float4*)(A + (long)arc * 64 + kofs);
        float4 p0 = ap[0], p1 = ap[1], p2 = ap[8], p3 = ap[9];
        f16x8 a0, a1;
        a0[0] = (_Float16)p0.x; a0[1] = (_Float16)p0.y;
        a0[2] = (_Float16)p0.z; a0[3] = (_Float16)p0.w;
        a0[4] = (_Float16)p1.x; a0[5] = (_Float16)p1.y;
        a0[6] = (_Float16)p1.z; a0[7] = (_Float16)p1.w;
        a1[0] = (_Float16)p2.x; a1[1] = (_Float16)p2.y;
        a1[2] = (_Float16)p2.z; a1[3] = (_Float16)p2.w;
        a1[4] = (_Float16)p3.x; a1[5] = (_Float16)p3.y;
        a1[6] = (_Float16)p3.z; a1[7] = (_Float16)p3.w;

        f32x4 z = {0.f, 0.f, 0.f, 0.f};
        f32x4 acc[4] = {z, z, z, z};
#pragma unroll
        for (int n = 0; n < 4; ++n) {
            acc[n] = __builtin_amdgcn_mfma_f32_16x16x32_f16(a0, b[n][0], acc[n], 0, 0, 0);
            acc[n] = __builtin_amdgcn_mfma_f32_16x16x32_f16(a1, b[n][1], acc[n], 0, 0, 0);
        }

        int orow0 = rb + lg * 4;
        if (!job2) {
#pragma unroll
            for (int r = 0; r < 4; ++r) {
                int row = orow0 + r;
                if (row < NN) {
                    float di = dinv[row];
#pragma unroll
                    for (int n = 0; n < 4; ++n)
                        g[(long)row * D + n * 16 + lr] = __float2half(acc[n][r] * di);
                }
            }
        } else {
#pragma unroll
            for (int r = 0; r < 4; ++r) {
                int row = orow0 + r;
                if (row < NN) {
#pragma unroll
                    for (int n = 0; n < 4; ++n)
                        out[(long)row * D + n * 16 + lr] = acc[n][r] + bsv[n];
                }
            }
        }
    }
}

// ---------- fused sort + gather: one block (512 thr) per 128-node bin ----------
__global__ __launch_bounds__(512) void k_gather(
    const int* __restrict__ bsum, unsigned* __restrict__ ebuf,
    const __half* __restrict__ g, float* __restrict__ out)
{
    __shared__ unsigned cache[CAPS];      // edges, then (in-place) sorted srcs
    __shared__ int c[128];                // degree counts (kept for dinv)
    __shared__ int cur[128];              // placement cursors
    __shared__ int rs_l[129];             // local row starts
    __shared__ int binoff_l[NB + 1];
    int t = threadIdx.x, b = blockIdx.x;
    int lane = t & 63, w = t >> 6;        // 8 waves

    scan_bsum_wave0(bsum, binoff_l, t);
    if (t < 128) c[t] = 0;
    __syncthreads();
    int e0 = binoff_l[b];
    int cnt = binoff_l[b + 1] - e0;

    // phase 1: stage to LDS + count
    for (int i = t; i < cnt; i += 512) {
        unsigned u = ebuf[e0 + i];
        if (i < CAPS) cache[i] = u;
        atomicAdd(&c[u & BMSK], 1);
    }
    __syncthreads();

    // phase 2: wave-0 scan of 128 counts
    if (t < 64) {
        int l0 = c[2 * t], l1 = c[2 * t + 1];
        int run = l0 + l1;
        int pre = run;
#pragma unroll
        for (int off = 1; off < 64; off <<= 1) {
            int u = __shfl_up(pre, off);
            if (t >= off) pre += u;
        }
        pre -= run;
        rs_l[2 * t] = pre;          cur[2 * t] = pre;
        rs_l[2 * t + 1] = pre + l0; cur[2 * t + 1] = pre + l0;
        if (t == 63) rs_l[128] = pre + run;   // == cnt
    }

    // phase 3a: stage all my edges into registers (before barrier)
    unsigned ur[8]; int nmy = 0;
    for (int i = t, j = 0; i < cnt && j < 8; i += 512, ++j) {
        ur[j] = (i < CAPS) ? cache[i] : ebuf[e0 + i];
        nmy = j + 1;
    }
    __syncthreads();
    // phase 3b: place srcs (in-place into cache; overflow spills to ebuf)
    for (int j = 0; j < nmy; ++j) {
        unsigned u = ur[j];
        int p = atomicAdd(&cur[u & BMSK], 1);
        unsigned s = u >> BSH;
        if (p < CAPS) cache[p] = s; else ebuf[e0 + p] = s;
    }
    __syncthreads();

    // phase 4: per-node gather; wave w handles rows w, 8+w, ...
    int f = lane & 7;                 // 16B granule within 128B row
    int grp = lane >> 3;              // 8 edges per step
    const uint4* gq = (const uint4*)g;
    for (int p = 0; p < 16; ++p) {
        int r = p * 8 + w;
        int node = (b << BSH) + r;
        if (node >= NN) continue;
        int rs0 = rs_l[r];
        int nl = rs_l[r + 1] - rs0;
        float a0 = 0.f, a1 = 0.f, a2 = 0.f, a3 = 0.f;
        float a4 = 0.f, a5 = 0.f, a6 = 0.f, a7 = 0.f;
        int NG = (nl + 7) >> 3;
        for (int c2 = 0; c2 < NG; ++c2) {
            int idx = c2 * 8 + grp;
            int s = NN;
            if (idx < nl) {
                int ii = rs0 + idx;
                s = (ii < CAPS) ? (int)cache[ii] : (int)ebuf[e0 + ii];
            }
            uint4 u = gq[(long)s * 8 + f];
            __half2 h0 = *(__half2*)&u.x, h1 = *(__half2*)&u.y;
            __half2 h2 = *(__half2*)&u.z, h3 = *(__half2*)&u.w;
            a0 += __low2float(h0); a1 += __high2float(h0);
            a2 += __low2float(h1); a3 += __high2float(h1);
            a4 += __low2float(h2); a5 += __high2float(h2);
            a6 += __low2float(h3); a7 += __high2float(h3);
        }
#pragma unroll
        for (int mask = 8; mask <= 32; mask <<= 1) {
            a0 += __shfl_xor(a0, mask); a1 += __shfl_xor(a1, mask);
            a2 += __shfl_xor(a2, mask); a3 += __shfl_xor(a3, mask);
            a4 += __shfl_xor(a4, mask); a5 += __shfl_xor(a5, mask);
            a6 += __shfl_xor(a6, mask); a7 += __shfl_xor(a7, mask);
        }
        if (lane < 16) {
            int ff = lane & 7, hs = lane >> 3;
            uint4 u = gq[(long)node * 8 + ff];               // self row
            __half2 s0 = hs ? *(__half2*)&u.z : *(__half2*)&u.x;
            __half2 s1 = hs ? *(__half2*)&u.w : *(__half2*)&u.y;
            float b0 = hs ? a4 : a0, b1 = hs ? a5 : a1;
            float b2 = hs ? a6 : a2, b3 = hs ? a7 : a3;
            float di = rsqrtf((float)(c[r] + 1));
            float4* op = (float4*)(out + (long)node * D) + (ff * 2 + hs);
            float4 o = *op;
            o.x += (b0 + __low2float(s0)) * di;
            o.y += (b1 + __high2float(s0)) * di;
            o.z += (b2 + __low2float(s1)) * di;
            o.w += (b3 + __high2float(s1)) * di;
            *op = o;
        }
    }
}

extern "C" void kernel_launch(void* const* d_in, const int* in_sizes, int n_in,
                              void* d_out, int out_size, void* d_ws, size_t ws_size,
                              hipStream_t stream) {
    const float* x   = (const float*)d_in[0];
    const int*   ei  = (const int*)d_in[1];   // [2, NE] int32
    const float* pos = (const float*)d_in[2];
    const float* Wg  = (const float*)d_in[3];
    const float* bg  = (const float*)d_in[4];
    const float* Wp  = (const float*)d_in[5];
    const float* bp  = (const float*)d_in[6];
    float* out = (float*)d_out;

    const int* src = ei;
    const int* dst = ei + NE;

    // ws layout (~20.4 MiB):
    //   [0)          ebuf[NE] u32
    //   [6,400,000)  g[(NN+1)*D] half  (128B-aligned rows; row NN = zeros)
    //   [19,200,128) hist[SB*PAD] | bsum[784] | dinv[NN]
    char* Wb = (char*)d_ws;
    unsigned* ebuf = (unsigned*)Wb;
    __half*   g    = (__half*)(Wb + 6400000);
    int*      hist = (int*)(Wb + 19200128);
    int*      bsum = hist + SB * PAD;
    float*    dinv = (float*)(bsum + 784);

    void* prep_args[] = {(void*)&src, (void*)&dst, (void*)&hist,
                         (void*)&bsum, (void*)&ebuf, (void*)&dinv};
    hipLaunchCooperativeKernel((void*)k_prep, dim3(SB), dim3(1024),
                               prep_args, 0, stream);
    hipLaunchKernelGGL(k_mm,     dim3(1564), dim3(256), 0, stream,
                       x, Wg, dinv, g, pos, Wp, bg, bp, out);
    hipLaunchKernelGGL(k_gather, dim3(NB),   dim3(512), 0, stream,
                       bsum, ebuf, g, out);
}

// Round 11
// 381.813 us; speedup vs baseline: 1.4674x; 1.4674x over previous
//
#include <hip/hip_runtime.h>
#include <hip/hip_fp16.h>

#define NN 100000
#define NE 1600000
#define D  64

#define SB    256        // prep blocks (cooperative grid, 1 per CU)
#define CHUNK 6250       // NE / SB
#define BSH   7          // bin = dst >> 7  (128 nodes per bin)
#define BMSK  127
#define NB    782        // ceil(NN / 128)
#define PAD   784        // hist row stride (ints)
#define CAPS  2560       // LDS edge capacity per bin (mean 2046, ~11 sigma)

typedef __attribute__((ext_vector_type(8))) _Float16 f16x8;
typedef __attribute__((ext_vector_type(4))) float    f32x4;

// ---- lean grid barrier (epoch + counter, agent scope, s_sleep spin) ----
// bar[0] = arrival counter (must be 0 at kernel entry), bar[1] = epoch.
__device__ __forceinline__ void gbar(int* bar) {
    __syncthreads();
    if (threadIdx.x == 0) {
        __threadfence();                                  // flush my writes
        int ep = __hip_atomic_load(&bar[1], __ATOMIC_RELAXED,
                                   __HIP_MEMORY_SCOPE_AGENT);
        int a = __hip_atomic_fetch_add(&bar[0], 1, __ATOMIC_ACQ_REL,
                                       __HIP_MEMORY_SCOPE_AGENT);
        if (a == SB - 1) {
            __hip_atomic_store(&bar[0], 0, __ATOMIC_RELAXED,
                               __HIP_MEMORY_SCOPE_AGENT);
            __hip_atomic_store(&bar[1], ep + 1, __ATOMIC_RELEASE,
                               __HIP_MEMORY_SCOPE_AGENT);
        } else {
            while (__hip_atomic_load(&bar[1], __ATOMIC_ACQUIRE,
                                     __HIP_MEMORY_SCOPE_AGENT) == ep)
                __builtin_amdgcn_s_sleep(2);
        }
    }
    __syncthreads();
}

// wave-0 helper: exclusive scan of bsum[0..NB) -> binoff_l[0..NB]
__device__ __forceinline__ void scan_bsum_wave0(const int* __restrict__ bsum,
                                                int* binoff_l, int t) {
    if (t < 64) {
        int base = t * 13;                   // 64*13 = 832 >= 783
        int loc[13]; int run = 0;
#pragma unroll
        for (int j = 0; j < 13; ++j) {
            int idx = base + j;
            int v = (idx < NB) ? bsum[idx] : 0;
            loc[j] = run; run += v;
        }
        int pre = run;
#pragma unroll
        for (int off = 1; off < 64; off <<= 1) {
            int u = __shfl_up(pre, off);
            if (t >= off) pre += u;
        }
        pre -= run;                          // exclusive over lanes
#pragma unroll
        for (int j = 0; j < 13; ++j) {
            int idx = base + j;
            if (idx <= NB) binoff_l[idx] = pre + loc[j];
        }
    }
}

// ---------- fused preprocessing: hist -> scan -> scatter -> count ----------
// One cooperative kernel; hand-rolled gbar between phases. 256 x 1024.
union PrepSM {
    int h[NB];            // phase A
    int ps[256][33];      // phase B (tiled column scan), 33.8 KB
    int cur[NB];          // phase C
    int c[128];           // phase D
};

__global__ __launch_bounds__(1024) void k_prep(
    const int* __restrict__ src, const int* __restrict__ dst,
    int* __restrict__ hist, int* __restrict__ bsum,
    unsigned* __restrict__ ebuf, float* __restrict__ dinv,
    int* __restrict__ bar)
{
    __shared__ PrepSM sm;
    __shared__ int binoff_l[NB + 1];
    int t = threadIdx.x, blk = blockIdx.x;
    int e0 = blk * CHUNK;

    // ---- phase A: per-block bin histogram (LDS atomics) ----
    for (int i = t; i < NB; i += 1024) sm.h[i] = 0;
    __syncthreads();
    for (int e = e0 + t; e < e0 + CHUNK; e += 1024)
        atomicAdd(&sm.h[dst[e] >> BSH], 1);
    __syncthreads();
    for (int i = t; i < NB; i += 1024) hist[blk * PAD + i] = sm.h[i];
    gbar(bar);

    // ---- phase B: per-bin exclusive scan over 256 block counts ----
    // blocks 0..24 each own a 32-bin tile; coalesced stage/writeback.
    if (blk < 25) {
        int b0 = blk * 32;
        for (int i = t; i < 256 * 32; i += 1024) {
            int r = i >> 5, cc = i & 31;
            int bin = b0 + cc;
            sm.ps[r][cc] = (bin < NB) ? hist[r * PAD + bin] : 0;
        }
        __syncthreads();
        int w = t >> 6, lane = t & 63;
        for (int cc = w; cc < 32; cc += 16) {     // wave per column
            int base = lane * 4;
            int v0 = sm.ps[base][cc], v1 = sm.ps[base + 1][cc];
            int v2 = sm.ps[base + 2][cc], v3 = sm.ps[base + 3][cc];
            int run = v0 + v1 + v2 + v3;
            int pre = run;
#pragma unroll
            for (int off = 1; off < 64; off <<= 1) {
                int u = __shfl_up(pre, off);
                if (lane >= off) pre += u;
            }
            pre -= run;
            sm.ps[base][cc]     = pre;
            sm.ps[base + 1][cc] = pre + v0;
            sm.ps[base + 2][cc] = pre + v0 + v1;
            sm.ps[base + 3][cc] = pre + v0 + v1 + v2;
            if (lane == 63 && b0 + cc < NB) bsum[b0 + cc] = pre + run;
        }
        __syncthreads();
        for (int i = t; i < 256 * 32; i += 1024) {
            int r = i >> 5, cc = i & 31;
            int bin = b0 + cc;
            if (bin < NB) hist[r * PAD + bin] = sm.ps[r][cc];
        }
    }
    gbar(bar);

    // ---- phase C: scatter packed (src<<7 | dloc) into bin-contiguous ebuf ----
    scan_bsum_wave0(bsum, binoff_l, t);
    __syncthreads();
    for (int i = t; i < NB; i += 1024)
        sm.cur[i] = binoff_l[i] + hist[blk * PAD + i];   // coalesced
    __syncthreads();
    for (int e = e0 + t; e < e0 + CHUNK; e += 1024) {
        int d = dst[e];
        int p = atomicAdd(&sm.cur[d >> BSH], 1);         // LDS atomic
        ebuf[p] = ((unsigned)src[e] << BSH) | (unsigned)(d & BMSK);
    }
    gbar(bar);

    // ---- phase D: per-bin degree count -> dinv (grid-stride over bins) ----
    for (int b = blk; b < NB; b += SB) {
        if (t < 128) sm.c[t] = 0;
        __syncthreads();
        int s0 = binoff_l[b], s1 = binoff_l[b + 1];
        for (int e = s0 + t; e < s1; e += 1024)
            atomicAdd(&sm.c[ebuf[e] & BMSK], 1);
        __syncthreads();
        if (t < 128) {
            int node = (b << BSH) + t;
            if (node < NN) dinv[node] = rsqrtf((float)(sm.c[t] + 1));
        }
        __syncthreads();
    }
}

// ---------- fused MFMA GEMMs: blocks [0,half): g = half(x@Wg * dinv)
//                              blocks [half,2*half): out = pos@Wp + bg + bp ----------
__global__ __launch_bounds__(256) void k_mm(
    const float* __restrict__ x, const float* __restrict__ Wg,
    const float* __restrict__ dinv, __half* __restrict__ g,
    const float* __restrict__ pos, const float* __restrict__ Wp,
    const float* __restrict__ bg, const float* __restrict__ bp,
    float* __restrict__ out)
{
    __shared__ __align__(16) _Float16 Wt[64][64];   // Wt[n][k] = W[k][n]
    int t = threadIdx.x;
    int lane = t & 63;
    int wid = t >> 6;
    int half_grid = gridDim.x >> 1;
    bool job2 = blockIdx.x >= half_grid;
    int blk = job2 ? (blockIdx.x - half_grid) : blockIdx.x;
    const float* A = job2 ? pos : x;
    const float* W = job2 ? Wp : Wg;

    // zero-pad row g[NN] (gather's invalid-edge target)
    if (blockIdx.x == 0 && t < 64) g[(long)NN * D + t] = __float2half(0.f);

    for (int i = t; i < 64 * 64; i += 256) {
        int k = i >> 6, n = i & 63;
        Wt[n][k] = (_Float16)W[i];
    }
    __syncthreads();

    int lr = lane & 15;        // A-row / C-col within tile
    int lg = lane >> 4;        // k-group / C-row-group
    int kofs = lg * 8;

    f16x8 b[4][2];             // hoisted B frags: [col-tile][k-tile]
#pragma unroll
    for (int n = 0; n < 4; ++n)
#pragma unroll
        for (int kt = 0; kt < 2; ++kt)
            b[n][kt] = *(const f16x8*)&Wt[n * 16 + lr][kt * 32 + kofs];

    float bsv[4] = {0.f, 0.f, 0.f, 0.f};
    if (job2) {
#pragma unroll
        for (int n = 0; n < 4; ++n) {
            int cc = n * 16 + lr;
            bsv[n] = bg[cc] + bp[cc];
        }
    }

    for (int rb0 = blk * 64; rb0 < NN; rb0 += half_grid * 64) {
        int rb = rb0 + wid * 16;
        int arow = rb + lr;
        int arc = arow < NN ? arow : NN - 1;
        const float4* ap = (const float4*)(A + (long)arc * 64 + kofs);
        float4 p0 = ap[0], p1 = ap[1], p2 = ap[8], p3 = ap[9];
        f16x8 a0, a1;
        a0[0] = (_Float16)p0.x; a0[1] = (_Float16)p0.y;
        a0[2] = (_Float16)p0.z; a0[3] = (_Float16)p0.w;
        a0[4] = (_Float16)p1.x; a0[5] = (_Float16)p1.y;
        a0[6] = (_Float16)p1.z; a0[7] = (_Float16)p1.w;
        a1[0] = (_Float16)p2.x; a1[1] = (_Float16)p2.y;
        a1[2] = (_Float16)p2.z; a1[3] = (_Float16)p2.w;
        a1[4] = (_Float16)p3.x; a1[5] = (_Float16)p3.y;
        a1[6] = (_Float16)p3.z; a1[7] = (_Float16)p3.w;

        f32x4 z = {0.f, 0.f, 0.f, 0.f};
        f32x4 acc[4] = {z, z, z, z};
#pragma unroll
        for (int n = 0; n < 4; ++n) {
            acc[n] = __builtin_amdgcn_mfma_f32_16x16x32_f16(a0, b[n][0], acc[n], 0, 0, 0);
            acc[n] = __builtin_amdgcn_mfma_f32_16x16x32_f16(a1, b[n][1], acc[n], 0, 0, 0);
        }

        int orow0 = rb + lg * 4;
        if (!job2) {
#pragma unroll
            for (int r = 0; r < 4; ++r) {
                int row = orow0 + r;
                if (row < NN) {
                    float di = dinv[row];
#pragma unroll
                    for (int n = 0; n < 4; ++n)
                        g[(long)row * D + n * 16 + lr] = __float2half(acc[n][r] * di);
                }
            }
        } else {
#pragma unroll
            for (int r = 0; r < 4; ++r) {
                int row = orow0 + r;
                if (row < NN) {
#pragma unroll
                    for (int n = 0; n < 4; ++n)
                        out[(long)row * D + n * 16 + lr] = acc[n][r] + bsv[n];
                }
            }
        }
    }
}

// ---------- fused sort + gather: one block (512 thr) per 128-node bin ----------
__global__ __launch_bounds__(512) void k_gather(
    const int* __restrict__ bsum, unsigned* __restrict__ ebuf,
    const __half* __restrict__ g, float* __restrict__ out)
{
    __shared__ unsigned cache[CAPS];      // edges, then (in-place) sorted srcs
    __shared__ int c[128];                // degree counts (kept for dinv)
    __shared__ int cur[128];              // placement cursors
    __shared__ int rs_l[129];             // local row starts
    __shared__ int binoff_l[NB + 1];
    int t = threadIdx.x, b = blockIdx.x;
    int lane = t & 63, w = t >> 6;        // 8 waves

    scan_bsum_wave0(bsum, binoff_l, t);
    if (t < 128) c[t] = 0;
    __syncthreads();
    int e0 = binoff_l[b];
    int cnt = binoff_l[b + 1] - e0;

    // phase 1: stage to LDS + count
    for (int i = t; i < cnt; i += 512) {
        unsigned u = ebuf[e0 + i];
        if (i < CAPS) cache[i] = u;
        atomicAdd(&c[u & BMSK], 1);
    }
    __syncthreads();

    // phase 2: wave-0 scan of 128 counts
    if (t < 64) {
        int l0 = c[2 * t], l1 = c[2 * t + 1];
        int run = l0 + l1;
        int pre = run;
#pragma unroll
        for (int off = 1; off < 64; off <<= 1) {
            int u = __shfl_up(pre, off);
            if (t >= off) pre += u;
        }
        pre -= run;
        rs_l[2 * t] = pre;          cur[2 * t] = pre;
        rs_l[2 * t + 1] = pre + l0; cur[2 * t + 1] = pre + l0;
        if (t == 63) rs_l[128] = pre + run;   // == cnt
    }

    // phase 3a: stage all my edges into registers (before barrier)
    unsigned ur[8]; int nmy = 0;
    for (int i = t, j = 0; i < cnt && j < 8; i += 512, ++j) {
        ur[j] = (i < CAPS) ? cache[i] : ebuf[e0 + i];
        nmy = j + 1;
    }
    __syncthreads();
    // phase 3b: place srcs (in-place into cache; overflow spills to ebuf)
    for (int j = 0; j < nmy; ++j) {
        unsigned u = ur[j];
        int p = atomicAdd(&cur[u & BMSK], 1);
        unsigned s = u >> BSH;
        if (p < CAPS) cache[p] = s; else ebuf[e0 + p] = s;
    }
    __syncthreads();

    // phase 4: per-node gather; wave w handles rows w, 8+w, ...
    int f = lane & 7;                 // 16B granule within 128B row
    int grp = lane >> 3;              // 8 edges per step
    const uint4* gq = (const uint4*)g;
    for (int p = 0; p < 16; ++p) {
        int r = p * 8 + w;
        int node = (b << BSH) + r;
        if (node >= NN) continue;
        int rs0 = rs_l[r];
        int nl = rs_l[r + 1] - rs0;
        float a0 = 0.f, a1 = 0.f, a2 = 0.f, a3 = 0.f;
        float a4 = 0.f, a5 = 0.f, a6 = 0.f, a7 = 0.f;
        int NG = (nl + 7) >> 3;
#pragma unroll 2
        for (int c2 = 0; c2 < NG; ++c2) {
            int idx = c2 * 8 + grp;
            int s = NN;
            if (idx < nl) {
                int ii = rs0 + idx;
                s = (ii < CAPS) ? (int)cache[ii] : (int)ebuf[e0 + ii];
            }
            uint4 u = gq[(long)s * 8 + f];
            __half2 h0 = *(__half2*)&u.x, h1 = *(__half2*)&u.y;
            __half2 h2 = *(__half2*)&u.z, h3 = *(__half2*)&u.w;
            a0 += __low2float(h0); a1 += __high2float(h0);
            a2 += __low2float(h1); a3 += __high2float(h1);
            a4 += __low2float(h2); a5 += __high2float(h2);
            a6 += __low2float(h3); a7 += __high2float(h3);
        }
#pragma unroll
        for (int mask = 8; mask <= 32; mask <<= 1) {
            a0 += __shfl_xor(a0, mask); a1 += __shfl_xor(a1, mask);
            a2 += __shfl_xor(a2, mask); a3 += __shfl_xor(a3, mask);
            a4 += __shfl_xor(a4, mask); a5 += __shfl_xor(a5, mask);
            a6 += __shfl_xor(a6, mask); a7 += __shfl_xor(a7, mask);
        }
        if (lane < 16) {
            int ff = lane & 7, hs = lane >> 3;
            uint4 u = gq[(long)node * 8 + ff];               // self row
            __half2 s0 = hs ? *(__half2*)&u.z : *(__half2*)&u.x;
            __half2 s1 = hs ? *(__half2*)&u.w : *(__half2*)&u.y;
            float b0 = hs ? a4 : a0, b1 = hs ? a5 : a1;
            float b2 = hs ? a6 : a2, b3 = hs ? a7 : a3;
            float di = rsqrtf((float)(c[r] + 1));
            float4* op = (float4*)(out + (long)node * D) + (ff * 2 + hs);
            float4 o = *op;
            o.x += (b0 + __low2float(s0)) * di;
            o.y += (b1 + __high2float(s0)) * di;
            o.z += (b2 + __low2float(s1)) * di;
            o.w += (b3 + __high2float(s1)) * di;
            *op = o;
        }
    }
}

extern "C" void kernel_launch(void* const* d_in, const int* in_sizes, int n_in,
                              void* d_out, int out_size, void* d_ws, size_t ws_size,
                              hipStream_t stream) {
    const float* x   = (const float*)d_in[0];
    const int*   ei  = (const int*)d_in[1];   // [2, NE] int32
    const float* pos = (const float*)d_in[2];
    const float* Wg  = (const float*)d_in[3];
    const float* bg  = (const float*)d_in[4];
    const float* Wp  = (const float*)d_in[5];
    const float* bp  = (const float*)d_in[6];
    float* out = (float*)d_out;

    const int* src = ei;
    const int* dst = ei + NE;

    // ws layout (~20.4 MiB):
    //   [0)          ebuf[NE] u32
    //   [6,400,000)  g[(NN+1)*D] half  (128B-aligned rows; row NN = zeros)
    //   [19,200,128) hist[SB*PAD] | bsum[784] | dinv[NN] | bar[2]
    char* Wb = (char*)d_ws;
    unsigned* ebuf = (unsigned*)Wb;
    __half*   g    = (__half*)(Wb + 6400000);
    int*      hist = (int*)(Wb + 19200128);
    int*      bsum = hist + SB * PAD;
    float*    dinv = (float*)(bsum + 784);
    int*      bar  = (int*)(dinv + NN);

    hipMemsetAsync(bar, 0, 2 * sizeof(int), stream);

    void* prep_args[] = {(void*)&src, (void*)&dst, (void*)&hist,
                         (void*)&bsum, (void*)&ebuf, (void*)&dinv, (void*)&bar};
    hipLaunchCooperativeKernel((void*)k_prep, dim3(SB), dim3(1024),
                               prep_args, 0, stream);
    hipLaunchKernelGGL(k_mm,     dim3(1564), dim3(256), 0, stream,
                       x, Wg, dinv, g, pos, Wp, bg, bp, out);
    hipLaunchKernelGGL(k_gather, dim3(NB),   dim3(512), 0, stream,
                       bsum, ebuf, g, out);
}

// Round 12
// 213.970 us; speedup vs baseline: 2.6184x; 1.7844x over previous
//
#include <hip/hip_runtime.h>
#include <hip/hip_fp16.h>

#define NN 100000
#define NE 1600000
#define D  64

#define SB    256        // hist/scatter blocks
#define CHUNK 6250       // NE / SB
#define BSH   7          // bin = dst >> 7  (128 nodes per bin)
#define BMSK  127
#define NB    782        // ceil(NN / 128)
#define PAD   784        // hist row stride (ints)
#define CAPS  2560       // LDS edge capacity per bin (mean 2046, ~11 sigma)

typedef __attribute__((ext_vector_type(8))) _Float16 f16x8;
typedef __attribute__((ext_vector_type(4))) float    f32x4;

// wave-0 helper: exclusive scan of bsum[0..NB) -> binoff_l[0..NB]
__device__ __forceinline__ void scan_bsum_wave0(const int* __restrict__ bsum,
                                                int* binoff_l, int t) {
    if (t < 64) {
        int base = t * 13;                   // 64*13 = 832 >= 783
        int loc[13]; int run = 0;
#pragma unroll
        for (int j = 0; j < 13; ++j) {
            int idx = base + j;
            int v = (idx < NB) ? bsum[idx] : 0;
            loc[j] = run; run += v;
        }
        int pre = run;
#pragma unroll
        for (int off = 1; off < 64; off <<= 1) {
            int u = __shfl_up(pre, off);
            if (t >= off) pre += u;
        }
        pre -= run;                          // exclusive over lanes
#pragma unroll
        for (int j = 0; j < 13; ++j) {
            int idx = base + j;
            if (idx <= NB) binoff_l[idx] = pre + loc[j];
        }
    }
}

// ---------- L1: blocks [0,782): out = pos@Wp + bg + bp  (independent GEMM)
//               blocks [782,1038): per-block bin histogram ----------
__global__ __launch_bounds__(256) void k_mm2hist(
    const float* __restrict__ pos, const float* __restrict__ Wp,
    const float* __restrict__ bg, const float* __restrict__ bp,
    float* __restrict__ out,
    const int* __restrict__ dst, int* __restrict__ hist)
{
    __shared__ union {
        __align__(16) _Float16 Wt[64][64];
        int h[NB];
    } sm;
    int t = threadIdx.x;

    if (blockIdx.x >= 782) {                 // ---- hist role ----
        int blk = blockIdx.x - 782;
        for (int i = t; i < NB; i += 256) sm.h[i] = 0;
        __syncthreads();
        int e0 = blk * CHUNK;
        for (int e = e0 + t; e < e0 + CHUNK; e += 256)
            atomicAdd(&sm.h[dst[e] >> BSH], 1);
        __syncthreads();
        for (int i = t; i < NB; i += 256) hist[blk * PAD + i] = sm.h[i];
        return;
    }

    // ---- mm2 role ----
    int lane = t & 63, wid = t >> 6;
    for (int i = t; i < 64 * 64; i += 256) {
        int k = i >> 6, n = i & 63;
        sm.Wt[n][k] = (_Float16)Wp[i];
    }
    __syncthreads();
    int lr = lane & 15, lg = lane >> 4;
    int kofs = lg * 8;
    f16x8 b[4][2];
#pragma unroll
    for (int n = 0; n < 4; ++n)
#pragma unroll
        for (int kt = 0; kt < 2; ++kt)
            b[n][kt] = *(const f16x8*)&sm.Wt[n * 16 + lr][kt * 32 + kofs];
    float bsv[4];
#pragma unroll
    for (int n = 0; n < 4; ++n) {
        int cc = n * 16 + lr;
        bsv[n] = bg[cc] + bp[cc];
    }
    for (int rb0 = blockIdx.x * 64; rb0 < NN; rb0 += 782 * 64) {
        int rb = rb0 + wid * 16;
        int arow = rb + lr;
        int arc = arow < NN ? arow : NN - 1;
        const float4* ap = (const float4*)(pos + (long)arc * 64 + kofs);
        float4 p0 = ap[0], p1 = ap[1], p2 = ap[8], p3 = ap[9];
        f16x8 a0, a1;
        a0[0] = (_Float16)p0.x; a0[1] = (_Float16)p0.y;
        a0[2] = (_Float16)p0.z; a0[3] = (_Float16)p0.w;
        a0[4] = (_Float16)p1.x; a0[5] = (_Float16)p1.y;
        a0[6] = (_Float16)p1.z; a0[7] = (_Float16)p1.w;
        a1[0] = (_Float16)p2.x; a1[1] = (_Float16)p2.y;
        a1[2] = (_Float16)p2.z; a1[3] = (_Float16)p2.w;
        a1[4] = (_Float16)p3.x; a1[5] = (_Float16)p3.y;
        a1[6] = (_Float16)p3.z; a1[7] = (_Float16)p3.w;
        f32x4 z = {0.f, 0.f, 0.f, 0.f};
        f32x4 acc[4] = {z, z, z, z};
#pragma unroll
        for (int n = 0; n < 4; ++n) {
            acc[n] = __builtin_amdgcn_mfma_f32_16x16x32_f16(a0, b[n][0], acc[n], 0, 0, 0);
            acc[n] = __builtin_amdgcn_mfma_f32_16x16x32_f16(a1, b[n][1], acc[n], 0, 0, 0);
        }
        int orow0 = rb + lg * 4;
#pragma unroll
        for (int r = 0; r < 4; ++r) {
            int row = orow0 + r;
            if (row < NN) {
#pragma unroll
                for (int n = 0; n < 4; ++n)
                    out[(long)row * 64 + n * 16 + lr] = acc[n][r] + bsv[n];
            }
        }
    }
}

// ---------- L2: scanT — per-bin exclusive scan, LDS-tiled & coalesced ----------
__global__ __launch_bounds__(1024) void k_scanT(int* __restrict__ hist,
                                                int* __restrict__ bsum) {
    __shared__ int ps[256][33];
    int t = threadIdx.x, b0 = blockIdx.x * 32;
    for (int i = t; i < 256 * 32; i += 1024) {   // stage (coalesced)
        int r = i >> 5, cc = i & 31;
        int bin = b0 + cc;
        ps[r][cc] = (bin < NB) ? hist[r * PAD + bin] : 0;
    }
    __syncthreads();
    int w = t >> 6, lane = t & 63;
    for (int cc = w; cc < 32; cc += 16) {        // wave per column
        int base = lane * 4;
        int v0 = ps[base][cc], v1 = ps[base + 1][cc];
        int v2 = ps[base + 2][cc], v3 = ps[base + 3][cc];
        int run = v0 + v1 + v2 + v3;
        int pre = run;
#pragma unroll
        for (int off = 1; off < 64; off <<= 1) {
            int u = __shfl_up(pre, off);
            if (lane >= off) pre += u;
        }
        pre -= run;
        ps[base][cc]     = pre;
        ps[base + 1][cc] = pre + v0;
        ps[base + 2][cc] = pre + v0 + v1;
        ps[base + 3][cc] = pre + v0 + v1 + v2;
        if (lane == 63 && b0 + cc < NB) bsum[b0 + cc] = pre + run;
    }
    __syncthreads();
    for (int i = t; i < 256 * 32; i += 1024) {   // writeback (coalesced)
        int r = i >> 5, cc = i & 31;
        int bin = b0 + cc;
        if (bin < NB) hist[r * PAD + bin] = ps[r][cc];
    }
}

// ---------- L3: scatter packed (src<<7 | dloc) into bin-contiguous ebuf ----------
__global__ __launch_bounds__(1024) void k_scatter1(
    const int* __restrict__ src, const int* __restrict__ dst,
    const int* __restrict__ hist, const int* __restrict__ bsum,
    unsigned* __restrict__ ebuf)
{
    __shared__ int cur[NB];
    __shared__ int binoff_l[NB + 1];
    int t = threadIdx.x, blk = blockIdx.x;
    scan_bsum_wave0(bsum, binoff_l, t);
    __syncthreads();
    for (int i = t; i < NB; i += 1024)
        cur[i] = binoff_l[i] + hist[blk * PAD + i];   // coalesced
    __syncthreads();
    int e0 = blk * CHUNK;
    for (int e = e0 + t; e < e0 + CHUNK; e += 1024) {
        int d = dst[e];
        int p = atomicAdd(&cur[d >> BSH], 1);         // LDS atomic
        ebuf[p] = ((unsigned)src[e] << BSH) | (unsigned)(d & BMSK);
    }
}

// ---------- L4: blocks [0,782): per-bin degree count -> dinv
//               blocks [782,1564): g = half(x@Wg)  (UNSCALED; independent) ----------
__global__ __launch_bounds__(512) void k_countmm1(
    const int* __restrict__ bsum, const unsigned* __restrict__ ebuf,
    float* __restrict__ dinv,
    const float* __restrict__ x, const float* __restrict__ Wg,
    __half* __restrict__ g)
{
    __shared__ union {
        struct { int c[128]; int binoff_l[NB + 1]; } cs;
        __align__(16) _Float16 Wt[64][64];
    } sm;
    int t = threadIdx.x;

    if (blockIdx.x < 782) {                  // ---- count role ----
        int b = blockIdx.x;
        scan_bsum_wave0(bsum, sm.cs.binoff_l, t);
        if (t < 128) sm.cs.c[t] = 0;
        __syncthreads();
        int e0 = sm.cs.binoff_l[b], e1 = sm.cs.binoff_l[b + 1];
        for (int e = e0 + t; e < e1; e += 512)
            atomicAdd(&sm.cs.c[ebuf[e] & BMSK], 1);
        __syncthreads();
        if (t < 128) {
            int node = (b << BSH) + t;
            if (node < NN) dinv[node] = rsqrtf((float)(sm.cs.c[t] + 1));
            else if (node == NN) dinv[node] = 0.f;    // pad row scale
        }
        return;
    }

    // ---- mm1 role (8 waves x 16 rows = 128 rows per block) ----
    int blk = blockIdx.x - 782;
    int lane = t & 63, wid = t >> 6;
    if (blk == 0 && t < 64) g[(long)NN * D + t] = __float2half(0.f);
    for (int i = t; i < 64 * 64; i += 512) {
        int k = i >> 6, n = i & 63;
        sm.Wt[n][k] = (_Float16)Wg[i];
    }
    __syncthreads();
    int lr = lane & 15, lg = lane >> 4;
    int kofs = lg * 8;
    f16x8 b[4][2];
#pragma unroll
    for (int n = 0; n < 4; ++n)
#pragma unroll
        for (int kt = 0; kt < 2; ++kt)
            b[n][kt] = *(const f16x8*)&sm.Wt[n * 16 + lr][kt * 32 + kofs];

    int rb = blk * 128 + wid * 16;           // 782*128 >= NN: single pass
    int arow = rb + lr;
    int arc = arow < NN ? arow : NN - 1;
    const float4* ap = (const float4*)(x + (long)arc * 64 + kofs);
    float4 p0 = ap[0], p1 = ap[1], p2 = ap[8], p3 = ap[9];
    f16x8 a0, a1;
    a0[0] = (_Float16)p0.x; a0[1] = (_Float16)p0.y;
    a0[2] = (_Float16)p0.z; a0[3] = (_Float16)p0.w;
    a0[4] = (_Float16)p1.x; a0[5] = (_Float16)p1.y;
    a0[6] = (_Float16)p1.z; a0[7] = (_Float16)p1.w;
    a1[0] = (_Float16)p2.x; a1[1] = (_Float16)p2.y;
    a1[2] = (_Float16)p2.z; a1[3] = (_Float16)p2.w;
    a1[4] = (_Float16)p3.x; a1[5] = (_Float16)p3.y;
    a1[6] = (_Float16)p3.z; a1[7] = (_Float16)p3.w;
    f32x4 z = {0.f, 0.f, 0.f, 0.f};
    f32x4 acc[4] = {z, z, z, z};
#pragma unroll
    for (int n = 0; n < 4; ++n) {
        acc[n] = __builtin_amdgcn_mfma_f32_16x16x32_f16(a0, b[n][0], acc[n], 0, 0, 0);
        acc[n] = __builtin_amdgcn_mfma_f32_16x16x32_f16(a1, b[n][1], acc[n], 0, 0, 0);
    }
    int orow0 = rb + lg * 4;
#pragma unroll
    for (int r = 0; r < 4; ++r) {
        int row = orow0 + r;
        if (row < NN) {
#pragma unroll
            for (int n = 0; n < 4; ++n)
                g[(long)row * D + n * 16 + lr] = __float2half(acc[n][r]);
        }
    }
}

// ---------- L5: fused sort + gather; per-edge dinv[s] fmaf ----------
__global__ __launch_bounds__(512) void k_gather(
    const int* __restrict__ bsum, unsigned* __restrict__ ebuf,
    const float* __restrict__ dinv, const __half* __restrict__ g,
    float* __restrict__ out)
{
    __shared__ unsigned cache[CAPS];      // edges, then (in-place) sorted srcs
    __shared__ int c[128];                // degree counts
    __shared__ int cur[128];              // placement cursors
    __shared__ int rs_l[129];             // local row starts
    __shared__ int binoff_l[NB + 1];
    int t = threadIdx.x, b = blockIdx.x;
    int lane = t & 63, w = t >> 6;        // 8 waves

    scan_bsum_wave0(bsum, binoff_l, t);
    if (t < 128) c[t] = 0;
    __syncthreads();
    int e0 = binoff_l[b];
    int cnt = binoff_l[b + 1] - e0;

    // phase 1: stage to LDS + count
    for (int i = t; i < cnt; i += 512) {
        unsigned u = ebuf[e0 + i];
        if (i < CAPS) cache[i] = u;
        atomicAdd(&c[u & BMSK], 1);
    }
    __syncthreads();

    // phase 2: wave-0 scan of 128 counts
    if (t < 64) {
        int l0 = c[2 * t], l1 = c[2 * t + 1];
        int run = l0 + l1;
        int pre = run;
#pragma unroll
        for (int off = 1; off < 64; off <<= 1) {
            int u = __shfl_up(pre, off);
            if (t >= off) pre += u;
        }
        pre -= run;
        rs_l[2 * t] = pre;          cur[2 * t] = pre;
        rs_l[2 * t + 1] = pre + l0; cur[2 * t + 1] = pre + l0;
        if (t == 63) rs_l[128] = pre + run;   // == cnt
    }

    // phase 3a: stage all my edges into registers (before barrier)
    unsigned ur[8]; int nmy = 0;
    for (int i = t, j = 0; i < cnt && j < 8; i += 512, ++j) {
        ur[j] = (i < CAPS) ? cache[i] : ebuf[e0 + i];
        nmy = j + 1;
    }
    __syncthreads();
    // phase 3b: place srcs (in-place into cache; overflow spills to ebuf)
    for (int j = 0; j < nmy; ++j) {
        unsigned u = ur[j];
        int p = atomicAdd(&cur[u & BMSK], 1);
        unsigned s = u >> BSH;
        if (p < CAPS) cache[p] = s; else ebuf[e0 + p] = s;
    }
    __syncthreads();

    // phase 4: per-node gather; wave w handles rows w, 8+w, ...
    int f = lane & 7;                 // 16B granule within 128B row
    int grp = lane >> 3;              // 8 edges per step
    const uint4* gq = (const uint4*)g;
    for (int p = 0; p < 16; ++p) {
        int r = p * 8 + w;
        int node = (b << BSH) + r;
        if (node >= NN) continue;
        int rs0 = rs_l[r];
        int nl = rs_l[r + 1] - rs0;
        float a0 = 0.f, a1 = 0.f, a2 = 0.f, a3 = 0.f;
        float a4 = 0.f, a5 = 0.f, a6 = 0.f, a7 = 0.f;
        int NG = (nl + 7) >> 3;
#pragma unroll 2
        for (int c2 = 0; c2 < NG; ++c2) {
            int idx = c2 * 8 + grp;
            int s = NN;
            if (idx < nl) {
                int ii = rs0 + idx;
                s = (ii < CAPS) ? (int)cache[ii] : (int)ebuf[e0 + ii];
            }
            uint4 u = gq[(long)s * 8 + f];
            float ds = dinv[s];                       // L2-resident table
            __half2 h0 = *(__half2*)&u.x, h1 = *(__half2*)&u.y;
            __half2 h2 = *(__half2*)&u.z, h3 = *(__half2*)&u.w;
            a0 = fmaf(ds, __low2float(h0), a0); a1 = fmaf(ds, __high2float(h0), a1);
            a2 = fmaf(ds, __low2float(h1), a2); a3 = fmaf(ds, __high2float(h1), a3);
            a4 = fmaf(ds, __low2float(h2), a4); a5 = fmaf(ds, __high2float(h2), a5);
            a6 = fmaf(ds, __low2float(h3), a6); a7 = fmaf(ds, __high2float(h3), a7);
        }
#pragma unroll
        for (int mask = 8; mask <= 32; mask <<= 1) {
            a0 += __shfl_xor(a0, mask); a1 += __shfl_xor(a1, mask);
            a2 += __shfl_xor(a2, mask); a3 += __shfl_xor(a3, mask);
            a4 += __shfl_xor(a4, mask); a5 += __shfl_xor(a5, mask);
            a6 += __shfl_xor(a6, mask); a7 += __shfl_xor(a7, mask);
        }
        if (lane < 16) {
            int ff = lane & 7, hs = lane >> 3;
            uint4 u = gq[(long)node * 8 + ff];               // self row (unscaled)
            __half2 s0 = hs ? *(__half2*)&u.z : *(__half2*)&u.x;
            __half2 s1 = hs ? *(__half2*)&u.w : *(__half2*)&u.y;
            float b0 = hs ? a4 : a0, b1 = hs ? a5 : a1;
            float b2 = hs ? a6 : a2, b3 = hs ? a7 : a3;
            float di = rsqrtf((float)(c[r] + 1));
            float4* op = (float4*)(out + (long)node * D) + (ff * 2 + hs);
            float4 o = *op;
            o.x += (b0 + di * __low2float(s0)) * di;
            o.y += (b1 + di * __high2float(s0)) * di;
            o.z += (b2 + di * __low2float(s1)) * di;
            o.w += (b3 + di * __high2float(s1)) * di;
            *op = o;
        }
    }
}

extern "C" void kernel_launch(void* const* d_in, const int* in_sizes, int n_in,
                              void* d_out, int out_size, void* d_ws, size_t ws_size,
                              hipStream_t stream) {
    const float* x   = (const float*)d_in[0];
    const int*   ei  = (const int*)d_in[1];   // [2, NE] int32
    const float* pos = (const float*)d_in[2];
    const float* Wg  = (const float*)d_in[3];
    const float* bg  = (const float*)d_in[4];
    const float* Wp  = (const float*)d_in[5];
    const float* bp  = (const float*)d_in[6];
    float* out = (float*)d_out;

    const int* src = ei;
    const int* dst = ei + NE;

    // ws layout (~20.4 MiB):
    //   [0)          ebuf[NE] u32
    //   [6,400,000)  g[(NN+1)*D] half  (128B-aligned rows; row NN = zeros)
    //   [19,200,128) hist[SB*PAD] | bsum[784] | dinv[NN+4]
    char* Wb = (char*)d_ws;
    unsigned* ebuf = (unsigned*)Wb;
    __half*   g    = (__half*)(Wb + 6400000);
    int*      hist = (int*)(Wb + 19200128);
    int*      bsum = hist + SB * PAD;
    float*    dinv = (float*)(bsum + 784);

    hipLaunchKernelGGL(k_mm2hist,  dim3(1038), dim3(256),  0, stream,
                       pos, Wp, bg, bp, out, dst, hist);
    hipLaunchKernelGGL(k_scanT,    dim3(25),   dim3(1024), 0, stream, hist, bsum);
    hipLaunchKernelGGL(k_scatter1, dim3(SB),   dim3(1024), 0, stream,
                       src, dst, hist, bsum, ebuf);
    hipLaunchKernelGGL(k_countmm1, dim3(1564), dim3(512),  0, stream,
                       bsum, ebuf, dinv, x, Wg, g);
    hipLaunchKernelGGL(k_gather,   dim3(NB),   dim3(512),  0, stream,
                       bsum, ebuf, dinv, g, out);
}

// Round 13
// 187.848 us; speedup vs baseline: 2.9825x; 1.1391x over previous
//
#include <hip/hip_runtime.h>
#include <hip/hip_fp16.h>

#define NN 100000
#define NE 1600000
#define D  64

#define SB    256        // hist/scatter blocks
#define CHUNK 6250       // NE / SB
#define BSH   7          // bin = dst >> 7  (128 nodes per bin)
#define BMSK  127
#define NB    782        // ceil(NN / 128)
#define PAD   784        // hist row stride (ints)
#define CAPS  2560       // LDS edge capacity per bin (mean 2046, ~11 sigma)

typedef __attribute__((ext_vector_type(8))) _Float16 f16x8;
typedef __attribute__((ext_vector_type(4))) float    f32x4;

// wave-0 helper: exclusive scan of bsum[0..NB) -> binoff_l[0..NB]
__device__ __forceinline__ void scan_bsum_wave0(const int* __restrict__ bsum,
                                                int* binoff_l, int t) {
    if (t < 64) {
        int base = t * 13;                   // 64*13 = 832 >= 783
        int loc[13]; int run = 0;
#pragma unroll
        for (int j = 0; j < 13; ++j) {
            int idx = base + j;
            int v = (idx < NB) ? bsum[idx] : 0;
            loc[j] = run; run += v;
        }
        int pre = run;
#pragma unroll
        for (int off = 1; off < 64; off <<= 1) {
            int u = __shfl_up(pre, off);
            if (t >= off) pre += u;
        }
        pre -= run;                          // exclusive over lanes
#pragma unroll
        for (int j = 0; j < 13; ++j) {
            int idx = base + j;
            if (idx <= NB) binoff_l[idx] = pre + loc[j];
        }
    }
}

// ---------- hist: per-block bin counts, block-major (coalesced) ----------
__global__ __launch_bounds__(1024) void k_hist(const int* __restrict__ dst,
                                               int* __restrict__ hist) {
    __shared__ int h[NB];
    int t = threadIdx.x, blk = blockIdx.x;
    for (int i = t; i < NB; i += 1024) h[i] = 0;
    __syncthreads();
    int e0 = blk * CHUNK;
    for (int e = e0 + t; e < e0 + CHUNK; e += 1024)
        atomicAdd(&h[dst[e] >> BSH], 1);
    __syncthreads();
    for (int i = t; i < NB; i += 1024) hist[blk * PAD + i] = h[i];
}

// ---------- scanT: per-bin exclusive scan, LDS-tiled & coalesced ----------
__global__ __launch_bounds__(1024) void k_scanT(int* __restrict__ hist,
                                                int* __restrict__ bsum) {
    __shared__ int ps[256][33];
    int t = threadIdx.x, b0 = blockIdx.x * 32;
    for (int i = t; i < 256 * 32; i += 1024) {   // stage (coalesced)
        int r = i >> 5, cc = i & 31;
        int bin = b0 + cc;
        ps[r][cc] = (bin < NB) ? hist[r * PAD + bin] : 0;
    }
    __syncthreads();
    int w = t >> 6, lane = t & 63;
    for (int cc = w; cc < 32; cc += 16) {        // wave per column
        int base = lane * 4;
        int v0 = ps[base][cc], v1 = ps[base + 1][cc];
        int v2 = ps[base + 2][cc], v3 = ps[base + 3][cc];
        int run = v0 + v1 + v2 + v3;
        int pre = run;
#pragma unroll
        for (int off = 1; off < 64; off <<= 1) {
            int u = __shfl_up(pre, off);
            if (lane >= off) pre += u;
        }
        pre -= run;
        ps[base][cc]     = pre;
        ps[base + 1][cc] = pre + v0;
        ps[base + 2][cc] = pre + v0 + v1;
        ps[base + 3][cc] = pre + v0 + v1 + v2;
        if (lane == 63 && b0 + cc < NB) bsum[b0 + cc] = pre + run;
    }
    __syncthreads();
    for (int i = t; i < 256 * 32; i += 1024) {   // writeback (coalesced)
        int r = i >> 5, cc = i & 31;
        int bin = b0 + cc;
        if (bin < NB) hist[r * PAD + bin] = ps[r][cc];
    }
}

// ---------- scatter: packed (src<<7 | dloc) into bin-contiguous ebuf ----------
__global__ __launch_bounds__(1024) void k_scatter1(
    const int* __restrict__ src, const int* __restrict__ dst,
    const int* __restrict__ hist, const int* __restrict__ bsum,
    unsigned* __restrict__ ebuf)
{
    __shared__ int cur[NB];
    __shared__ int binoff_l[NB + 1];
    int t = threadIdx.x, blk = blockIdx.x;
    scan_bsum_wave0(bsum, binoff_l, t);
    __syncthreads();
    for (int i = t; i < NB; i += 1024)
        cur[i] = binoff_l[i] + hist[blk * PAD + i];   // coalesced
    __syncthreads();
    int e0 = blk * CHUNK;
    for (int e = e0 + t; e < e0 + CHUNK; e += 1024) {
        int d = dst[e];
        int p = atomicAdd(&cur[d >> BSH], 1);         // LDS atomic
        ebuf[p] = ((unsigned)src[e] << BSH) | (unsigned)(d & BMSK);
    }
}

// ---------- count: per-bin degrees -> dinv (needed by k_mm) ----------
__global__ __launch_bounds__(512) void k_count(const int* __restrict__ bsum,
                                               const unsigned* __restrict__ ebuf,
                                               float* __restrict__ dinv) {
    __shared__ int c[128];
    __shared__ int binoff_l[NB + 1];
    int t = threadIdx.x, b = blockIdx.x;
    scan_bsum_wave0(bsum, binoff_l, t);
    if (t < 128) c[t] = 0;
    __syncthreads();
    int e0 = binoff_l[b], e1 = binoff_l[b + 1];
    for (int e = e0 + t; e < e1; e += 512)
        atomicAdd(&c[ebuf[e] & BMSK], 1);
    __syncthreads();
    if (t < 128) {
        int node = (b << BSH) + t;
        if (node < NN) dinv[node] = rsqrtf((float)(c[t] + 1));
    }
}

// ---------- fused MFMA GEMMs: blocks [0,half): g = half(x@Wg * dinv)
//                              blocks [half,2*half): out = pos@Wp + bg + bp ----------
__global__ __launch_bounds__(256) void k_mm(
    const float* __restrict__ x, const float* __restrict__ Wg,
    const float* __restrict__ dinv, __half* __restrict__ g,
    const float* __restrict__ pos, const float* __restrict__ Wp,
    const float* __restrict__ bg, const float* __restrict__ bp,
    float* __restrict__ out)
{
    __shared__ __align__(16) _Float16 Wt[64][64];   // Wt[n][k] = W[k][n]
    int t = threadIdx.x;
    int lane = t & 63;
    int wid = t >> 6;
    int half_grid = gridDim.x >> 1;
    bool job2 = blockIdx.x >= half_grid;
    int blk = job2 ? (blockIdx.x - half_grid) : blockIdx.x;
    const float* A = job2 ? pos : x;
    const float* W = job2 ? Wp : Wg;

    // zero-pad row g[NN] (gather's invalid-edge target)
    if (blockIdx.x == 0 && t < 64) g[(long)NN * D + t] = __float2half(0.f);

    for (int i = t; i < 64 * 64; i += 256) {
        int k = i >> 6, n = i & 63;
        Wt[n][k] = (_Float16)W[i];
    }
    __syncthreads();

    int lr = lane & 15;        // A-row / C-col within tile
    int lg = lane >> 4;        // k-group / C-row-group
    int kofs = lg * 8;

    f16x8 b[4][2];             // hoisted B frags: [col-tile][k-tile]
#pragma unroll
    for (int n = 0; n < 4; ++n)
#pragma unroll
        for (int kt = 0; kt < 2; ++kt)
            b[n][kt] = *(const f16x8*)&Wt[n * 16 + lr][kt * 32 + kofs];

    float bsv[4] = {0.f, 0.f, 0.f, 0.f};
    if (job2) {
#pragma unroll
        for (int n = 0; n < 4; ++n) {
            int cc = n * 16 + lr;
            bsv[n] = bg[cc] + bp[cc];
        }
    }

    for (int rb0 = blk * 64; rb0 < NN; rb0 += half_grid * 64) {
        int rb = rb0 + wid * 16;
        int arow = rb + lr;
        int arc = arow < NN ? arow : NN - 1;
        const float4* ap = (const float4*)(A + (long)arc * 64 + kofs);
        float4 p0 = ap[0], p1 = ap[1], p2 = ap[8], p3 = ap[9];
        f16x8 a0, a1;
        a0[0] = (_Float16)p0.x; a0[1] = (_Float16)p0.y;
        a0[2] = (_Float16)p0.z; a0[3] = (_Float16)p0.w;
        a0[4] = (_Float16)p1.x; a0[5] = (_Float16)p1.y;
        a0[6] = (_Float16)p1.z; a0[7] = (_Float16)p1.w;
        a1[0] = (_Float16)p2.x; a1[1] = (_Float16)p2.y;
        a1[2] = (_Float16)p2.z; a1[3] = (_Float16)p2.w;
        a1[4] = (_Float16)p3.x; a1[5] = (_Float16)p3.y;
        a1[6] = (_Float16)p3.z; a1[7] = (_Float16)p3.w;

        f32x4 z = {0.f, 0.f, 0.f, 0.f};
        f32x4 acc[4] = {z, z, z, z};
#pragma unroll
        for (int n = 0; n < 4; ++n) {
            acc[n] = __builtin_amdgcn_mfma_f32_16x16x32_f16(a0, b[n][0], acc[n], 0, 0, 0);
            acc[n] = __builtin_amdgcn_mfma_f32_16x16x32_f16(a1, b[n][1], acc[n], 0, 0, 0);
        }

        int orow0 = rb + lg * 4;
        if (!job2) {
#pragma unroll
            for (int r = 0; r < 4; ++r) {
                int row = orow0 + r;
                if (row < NN) {
                    float di = dinv[row];
#pragma unroll
                    for (int n = 0; n < 4; ++n)
                        g[(long)row * D + n * 16 + lr] = __float2half(acc[n][r] * di);
                }
            }
        } else {
#pragma unroll
            for (int r = 0; r < 4; ++r) {
                int row = orow0 + r;
                if (row < NN) {
#pragma unroll
                    for (int n = 0; n < 4; ++n)
                        out[(long)row * D + n * 16 + lr] = acc[n][r] + bsv[n];
                }
            }
        }
    }
}

// ---------- fused sort + gather: one block (512 thr) per 128-node bin ----------
// phase 4: 8-lane group OWNS a row (no shfl reduce, no lane<16 divergence).
__global__ __launch_bounds__(512) void k_gather(
    const int* __restrict__ bsum, unsigned* __restrict__ ebuf,
    const __half* __restrict__ g, float* __restrict__ out)
{
    __shared__ unsigned cache[CAPS];      // edges, then (in-place) sorted srcs
    __shared__ int c[128];                // degree counts
    __shared__ int cur[128];              // placement cursors
    __shared__ int rs_l[129];             // local row starts
    __shared__ int binoff_l[NB + 1];
    int t = threadIdx.x, b = blockIdx.x;
    int lane = t & 63, w = t >> 6;        // 8 waves

    scan_bsum_wave0(bsum, binoff_l, t);
    if (t < 128) c[t] = 0;
    __syncthreads();
    int e0 = binoff_l[b];
    int cnt = binoff_l[b + 1] - e0;

    // phase 1: stage to LDS + count
    for (int i = t; i < cnt; i += 512) {
        unsigned u = ebuf[e0 + i];
        if (i < CAPS) cache[i] = u;
        atomicAdd(&c[u & BMSK], 1);
    }
    __syncthreads();

    // phase 2: wave-0 scan of 128 counts
    if (t < 64) {
        int l0 = c[2 * t], l1 = c[2 * t + 1];
        int run = l0 + l1;
        int pre = run;
#pragma unroll
        for (int off = 1; off < 64; off <<= 1) {
            int u = __shfl_up(pre, off);
            if (t >= off) pre += u;
        }
        pre -= run;
        rs_l[2 * t] = pre;          cur[2 * t] = pre;
        rs_l[2 * t + 1] = pre + l0; cur[2 * t + 1] = pre + l0;
        if (t == 63) rs_l[128] = pre + run;   // == cnt
    }

    // phase 3a: stage all my edges into registers (before barrier)
    unsigned ur[8]; int nmy = 0;
    for (int i = t, j = 0; i < cnt && j < 8; i += 512, ++j) {
        ur[j] = (i < CAPS) ? cache[i] : ebuf[e0 + i];
        nmy = j + 1;
    }
    __syncthreads();
    // phase 3b: place srcs (in-place into cache; overflow spills to ebuf)
    for (int j = 0; j < nmy; ++j) {
        unsigned u = ur[j];
        int p = atomicAdd(&cur[u & BMSK], 1);
        unsigned s = u >> BSH;
        if (p < CAPS) cache[p] = s; else ebuf[e0 + p] = s;
    }
    __syncthreads();

    // phase 4: group-owns-row gather. group grp of wave w handles
    // rows w*16 + grp and w*16 + 8 + grp. 32-bit indexing throughout.
    int f = lane & 7;                 // 16B granule within 128B row
    int grp = lane >> 3;              // group 0..7
    const uint4* gq = (const uint4*)g;
#pragma unroll
    for (int half = 0; half < 2; ++half) {
        int r = w * 16 + half * 8 + grp;
        int node = (b << BSH) + r;
        if (node < NN) {              // group-uniform predicate
            int rs0 = rs_l[r];
            int nl = rs_l[r + 1] - rs0;
            float a0 = 0.f, a1 = 0.f, a2 = 0.f, a3 = 0.f;
            float a4 = 0.f, a5 = 0.f, a6 = 0.f, a7 = 0.f;
#pragma unroll 4
            for (int k = 0; k < nl; ++k) {
                int ii = rs0 + k;
                int s = (ii < CAPS) ? (int)cache[ii] : (int)ebuf[e0 + ii];
                uint4 u = gq[s * 8 + f];              // 32-bit index
                __half2 h0 = *(__half2*)&u.x, h1 = *(__half2*)&u.y;
                __half2 h2 = *(__half2*)&u.z, h3 = *(__half2*)&u.w;
                a0 += __low2float(h0); a1 += __high2float(h0);
                a2 += __low2float(h1); a3 += __high2float(h1);
                a4 += __low2float(h2); a5 += __high2float(h2);
                a6 += __low2float(h3); a7 += __high2float(h3);
            }
            // epilogue: all 8 lanes; group covers the full 256B out row
            float di = rsqrtf((float)(c[r] + 1));
            uint4 su = gq[node * 8 + f];              // self row granule
            __half2 s0 = *(__half2*)&su.x, s1 = *(__half2*)&su.y;
            __half2 s2 = *(__half2*)&su.z, s3 = *(__half2*)&su.w;
            float4* op = (float4*)(out + node * 64 + f * 8);
            float4 o0 = op[0], o1 = op[1];
            o0.x += (a0 + __low2float(s0)) * di;
            o0.y += (a1 + __high2float(s0)) * di;
            o0.z += (a2 + __low2float(s1)) * di;
            o0.w += (a3 + __high2float(s1)) * di;
            o1.x += (a4 + __low2float(s2)) * di;
            o1.y += (a5 + __high2float(s2)) * di;
            o1.z += (a6 + __low2float(s3)) * di;
            o1.w += (a7 + __high2float(s3)) * di;
            op[0] = o0; op[1] = o1;
        }
    }
}

extern "C" void kernel_launch(void* const* d_in, const int* in_sizes, int n_in,
                              void* d_out, int out_size, void* d_ws, size_t ws_size,
                              hipStream_t stream) {
    const float* x   = (const float*)d_in[0];
    const int*   ei  = (const int*)d_in[1];   // [2, NE] int32
    const float* pos = (const float*)d_in[2];
    const float* Wg  = (const float*)d_in[3];
    const float* bg  = (const float*)d_in[4];
    const float* Wp  = (const float*)d_in[5];
    const float* bp  = (const float*)d_in[6];
    float* out = (float*)d_out;

    const int* src = ei;
    const int* dst = ei + NE;

    // ws layout (~20.4 MiB):
    //   [0)          ebuf[NE] u32
    //   [6,400,000)  g[(NN+1)*D] half  (128B-aligned rows; row NN = zeros)
    //   [19,200,128) hist[SB*PAD] | bsum[784] | dinv[NN]
    char* Wb = (char*)d_ws;
    unsigned* ebuf = (unsigned*)Wb;
    __half*   g    = (__half*)(Wb + 6400000);
    int*      hist = (int*)(Wb + 19200128);
    int*      bsum = hist + SB * PAD;
    float*    dinv = (float*)(bsum + 784);

    hipLaunchKernelGGL(k_hist,     dim3(SB),   dim3(1024), 0, stream, dst, hist);
    hipLaunchKernelGGL(k_scanT,    dim3(25),   dim3(1024), 0, stream, hist, bsum);
    hipLaunchKernelGGL(k_scatter1, dim3(SB),   dim3(1024), 0, stream,
                       src, dst, hist, bsum, ebuf);
    hipLaunchKernelGGL(k_count,    dim3(NB),   dim3(512),  0, stream,
                       bsum, ebuf, dinv);
    hipLaunchKernelGGL(k_mm,       dim3(1564), dim3(256),  0, stream,
                       x, Wg, dinv, g, pos, Wp, bg, bp, out);
    hipLaunchKernelGGL(k_gather,   dim3(NB),   dim3(512),  0, stream,
                       bsum, ebuf, g, out);
}